// Round 19
// baseline (371.937 us; speedup 1.0000x reference)
//
#include <hip/hip_runtime.h>
#include <hip/hip_bf16.h>

#define T_SEQ 2048
#define C_DIM 2048
#define L_DIM 512
#define H_NUM 16
#define S_DIM 128
#define B_SZ  2

typedef __attribute__((ext_vector_type(8))) short bf16x8;
typedef __attribute__((ext_vector_type(4))) float f32x4;
typedef __attribute__((ext_vector_type(4))) short short4v;

__device__ inline short f2bf(float f) {
    union { float f; unsigned u; } x; x.f = f;
    unsigned r = x.u + 0x7fffu + ((x.u >> 16) & 1u);
    return (short)(r >> 16);
}

// ---------- LDS-tiled weight transpose: in fp32 [R][C] -> out bf16 [C][R], 64x64 tiles ----------
__device__ __forceinline__ void wtile_body(const float* __restrict__ in, short* __restrict__ out,
                                           int R, int C, int r0, int c0, int tid) {
    __shared__ float lds[64][66];
    #pragma unroll
    for (int it = 0; it < 4; it++) {
        int r = (tid >> 4) + it * 16;
        int c4 = (tid & 15) * 4;
        float4 v = *(const float4*)&in[(long)(r0 + r) * C + c0 + c4];
        lds[c4 + 0][r] = v.x; lds[c4 + 1][r] = v.y;
        lds[c4 + 2][r] = v.z; lds[c4 + 3][r] = v.w;
    }
    __syncthreads();
    #pragma unroll
    for (int it = 0; it < 4; it++) {
        int c = tid >> 2;
        int rb = (tid & 3) * 16 + it * 4;
        short4v o;
        #pragma unroll
        for (int j = 0; j < 4; j++) o[j] = f2bf(lds[c][rb + j]);
        *(short4v*)&out[(long)(c0 + c) * R + r0 + rb] = o;
    }
}

// ---------- fused prep: x cast (blocks 0..8191) + 5 tiled weight transposes (8192..11007) ------
__global__ __launch_bounds__(256) void prep_kernel(
    const float* __restrict__ x, short* __restrict__ xb,
    const float* __restrict__ wq, short* __restrict__ wqT,
    const float* __restrict__ wdkv, short* __restrict__ wdkvT,
    const float* __restrict__ wuk, short* __restrict__ wukT,
    const float* __restrict__ wuv, short* __restrict__ wuvT,
    const float* __restrict__ wo, short* __restrict__ woT)
{
    int bid = blockIdx.x, tid = threadIdx.x;
    if (bid < 8192) {
        int i = bid * 256 + tid;                       // 8192*256 == 2097152 exactly
        float4 v = ((const float4*)x)[i];
        short4v o;
        o[0] = f2bf(v.x); o[1] = f2bf(v.y); o[2] = f2bf(v.z); o[3] = f2bf(v.w);
        ((short4v*)xb)[i] = o;
        return;
    }
    int t = bid - 8192;
    if (t < 1024)       wtile_body(wq,   wqT,   2048, 2048, (t >> 5) * 64,            (t & 31) * 64, tid);
    else if (t < 1280)  wtile_body(wdkv, wdkvT, 2048, 512,  ((t - 1024) >> 3) * 64,   ((t - 1024) & 7) * 64, tid);
    else if (t < 1536)  wtile_body(wuk,  wukT,  2048, 512,  ((t - 1280) >> 3) * 64,   ((t - 1280) & 7) * 64, tid);
    else if (t < 1792)  wtile_body(wuv,  wuvT,  512,  2048, ((t - 1536) >> 5) * 64,   ((t - 1536) & 31) * 64, tid);
    else                wtile_body(wo,   woT,   2048, 2048, ((t - 1792) >> 5) * 64,   ((t - 1792) & 31) * 64, tid);
}

// ---------- GEMM body: 128x128 tile, BK=32, dbuf LDS + counted vmcnt(4); cscale on output ------
// transout: epilogue transposes the tile via LDS (As reused as exactly-32KB scratch) and stores
// directly in vt[b][col][t] layout (b = m0>>11), coalesced b128. XOR swizzle row^((col&7)<<3).
__device__ __forceinline__ void gemm_body(
    const short* __restrict__ A, const short* __restrict__ Bt,
    float* __restrict__ Cf, short* __restrict__ Cb,
    int K, int lda, int ldb, int ldc, int m0, int n0, long coff, bool outf32, bool transout,
    float cscale, short (&As)[2][128 * 32], short (&Bs)[2][128 * 32])
{
    int tid = threadIdx.x;
    int wave = tid >> 6, l = tid & 63;
    int wm = (wave >> 1) * 64, wn = (wave & 1) * 64;
    int lr = l & 15, lhi = l >> 4;
    f32x4 acc[4][4] = {};

#define STAGE_AB(KI, BUF) do { \
        _Pragma("unroll") \
        for (int r = 0; r < 2; r++) { \
            int e = (r * 256 + tid) * 8; \
            int row = e >> 5, col = e & 31; \
            __builtin_amdgcn_global_load_lds( \
                (const __attribute__((address_space(1))) unsigned int*)(A + (long)(m0 + row) * lda + (KI) * 32 + col), \
                (__attribute__((address_space(3))) unsigned int*)(&As[BUF][e]), 16, 0, 0); \
            __builtin_amdgcn_global_load_lds( \
                (const __attribute__((address_space(1))) unsigned int*)(Bt + (long)(n0 + row) * ldb + (KI) * 32 + col), \
                (__attribute__((address_space(3))) unsigned int*)(&Bs[BUF][e]), 16, 0, 0); \
        } \
    } while (0)

    int nk = K >> 5;
    STAGE_AB(0, 0);

    for (int i = 0; i < nk; i++) {
        int cur = i & 1;
        asm volatile("s_waitcnt lgkmcnt(0)" ::: "memory");
        __builtin_amdgcn_s_barrier();
        if (i + 1 < nk) {
            STAGE_AB(i + 1, cur ^ 1);
            asm volatile("s_waitcnt vmcnt(4)" ::: "memory");
        } else {
            asm volatile("s_waitcnt vmcnt(0)" ::: "memory");
        }
        __builtin_amdgcn_s_barrier();

        bf16x8 af[4], bfr[4];
        #pragma unroll
        for (int mt = 0; mt < 4; mt++)
            af[mt] = *(const bf16x8*)&As[cur][(wm + mt * 16 + lr) * 32 + lhi * 8];
        #pragma unroll
        for (int nt = 0; nt < 4; nt++)
            bfr[nt] = *(const bf16x8*)&Bs[cur][(wn + nt * 16 + lr) * 32 + lhi * 8];
        #pragma unroll
        for (int mt = 0; mt < 4; mt++)
            #pragma unroll
            for (int nt = 0; nt < 4; nt++)
                acc[mt][nt] = __builtin_amdgcn_mfma_f32_16x16x32_bf16(af[mt], bfr[nt], acc[mt][nt], 0, 0, 0);
    }
#undef STAGE_AB

    if (!transout) {
        #pragma unroll
        for (int mt = 0; mt < 4; mt++) {
            #pragma unroll
            for (int i = 0; i < 4; i++) {
                int row = m0 + wm + mt * 16 + lhi * 4 + i;
                long base = coff + (long)row * ldc + n0 + wn;
                #pragma unroll
                for (int nt = 0; nt < 4; nt++) {
                    float val = acc[mt][nt][i] * cscale;
                    int colo = nt * 16 + lr;
                    if (outf32) Cf[base + colo] = val;
                    else        Cb[base + colo] = f2bf(val);
                }
            }
        }
    } else {
        // transpose tile in LDS, then coalesced store to vt[b][col][t]
        __syncthreads();
        short* sc = &As[0][0];                         // 128*128 shorts = exactly 32KB
        #pragma unroll
        for (int mt = 0; mt < 4; mt++) {
            int rowb = wm + mt * 16 + lhi * 4;
            #pragma unroll
            for (int nt = 0; nt < 4; nt++) {
                int col = wn + nt * 16 + lr;
                short4v pk;
                #pragma unroll
                for (int i = 0; i < 4; i++) pk[i] = f2bf(acc[mt][nt][i] * cscale);
                *(short4v*)&sc[col * 128 + (rowb ^ ((col & 7) << 3))] = pk;
            }
        }
        __syncthreads();
        long base = (long)(m0 >> 11) * T_SEQ * C_DIM + (m0 & 2047);
        #pragma unroll
        for (int it = 0; it < 8; it++) {
            int flat = it * 2048 + tid * 8;
            int col = flat >> 7, rowb = flat & 127;
            bf16x8 o = *(const bf16x8*)&sc[col * 128 + (rowb ^ ((col & 7) << 3))];
            *(bf16x8*)&Cb[base + (long)(n0 + col) * T_SEQ + rowb] = o;
        }
    }
}

// ---------- single-problem GEMM (used for the final out = y @ w_o, fp32 out) ----------
__global__ __launch_bounds__(256) void gemm_bt_kernel(
    const short* __restrict__ A, const short* __restrict__ Bt, float* __restrict__ Cf,
    int K, int lda, int ldb, int ldc)
{
    __shared__ __align__(16) short As[2][128 * 32];
    __shared__ __align__(16) short Bs[2][128 * 32];
    int m0 = blockIdx.y * 128, n0 = blockIdx.x * 128;
    gemm_body(A, Bt, Cf, nullptr, K, lda, ldb, ldc, m0, n0, 0, true, false, 1.0f, As, Bs);
}

// ---------- fused 2-problem GEMM: p0 blocks [0,nblk0), p1 after (1D decoded grid) ----------
__global__ __launch_bounds__(256) void gemm2_kernel(
    const short* A0, const short* Bt0, short* Cb0, int K0, int lda0, int ldb0, int ldc0,
    long sAz0, long sBz0, long sCz0, int nx0, int nxy0, int nblk0, float cscale0, int trans0,
    const short* A1, const short* Bt1, short* Cb1, int K1, int lda1, int ldb1, int ldc1,
    long sAz1, long sBz1, long sCz1, int nx1, int nxy1, float cscale1, int trans1)
{
    __shared__ __align__(16) short As[2][128 * 32];
    __shared__ __align__(16) short Bs[2][128 * 32];
    int id = blockIdx.x;
    const short *A, *Bt; short* Cb; int K, lda, ldb, ldc, nx, nxy, local, trans;
    long sAz, sBz, sCz; float cs;
    if (id < nblk0) {
        A = A0; Bt = Bt0; Cb = Cb0; K = K0; lda = lda0; ldb = ldb0; ldc = ldc0;
        sAz = sAz0; sBz = sBz0; sCz = sCz0; nx = nx0; nxy = nxy0; local = id; cs = cscale0;
        trans = trans0;
    } else {
        A = A1; Bt = Bt1; Cb = Cb1; K = K1; lda = lda1; ldb = ldb1; ldc = ldc1;
        sAz = sAz1; sBz = sBz1; sCz = sCz1; nx = nx1; nxy = nxy1; local = id - nblk0; cs = cscale1;
        trans = trans1;
    }
    int z = local / nxy, rem = local % nxy;
    int n0 = (rem % nx) * 128, m0 = (rem / nx) * 128;
    A += (long)z * sAz; Bt += (long)z * sBz;
    gemm_body(A, Bt, nullptr, Cb, K, lda, ldb, ldc, m0, n0, (long)z * sCz, false, trans != 0,
              cs, As, Bs);
}

// ------------- flash attention v18: flash16 + s_setprio(1) around MFMA clusters (T5) ----------
__global__ __launch_bounds__(256) void flash13_kernel(
    const short* __restrict__ qlat,  // [H][B][T][L]  (pre-scaled by 1/sqrt(C)*log2(e))
    const short* __restrict__ kv,    // [B][T][L]
    const short* __restrict__ vt,    // [B][H][S][T]
    short* __restrict__ y)           // [B][T][C]
{
    __shared__ __align__(16) short Ks[32 * 512];      // 32 KB, single buffer
    __shared__ __align__(16) short Ps[4 * 16 * 32];   // 4 KB (1 KB per wave, wave-private)

    int f = blockIdx.x;                               // 0..511
    int xcd = f & 7, slot = f >> 3;
    int b = xcd >> 2;
    int h = (xcd & 3) | ((slot >> 4) << 2);
    int pr = slot & 15;
    int tid = threadIdx.x;
    int w = tid >> 6, l = tid & 63, lr = l & 15, lhi = l >> 4;
    const short* qb  = qlat + ((long)(h * B_SZ + b)) * T_SEQ * L_DIM;
    const short* kvb = kv + (long)b * T_SEQ * L_DIM;
    const short* vtb = vt + ((long)(b * H_NUM + h)) * S_DIM * T_SEQ;
    char* Pwb = (char*)(Ps + w * 512);

    // stage chunk [32 rows] at kv row S0ROW into Ks (src pre-swizzled, dest linear; rule #21)
#define STAGE_K(S0ROW) do { \
        _Pragma("unroll") \
        for (int r = 0; r < 8; r++) { \
            int flat = r * 4096 + tid * 16; \
            int row = flat >> 10, colb = flat & 1023; \
            int src = (((S0ROW) + row) << 10) + (colb ^ ((row & 15) << 4)); \
            __builtin_amdgcn_global_load_lds( \
                (const __attribute__((address_space(1))) unsigned int*)((const char*)kvb + src), \
                (__attribute__((address_space(3))) unsigned int*)((char*)Ks + flat), 16, 0, 0); \
        } \
    } while (0)

    #pragma unroll 1
    for (int sel = 0; sel < 2; sel++) {
        int qt = sel ? pr : (31 - pr);                // heavy tile first
        int t0 = qt * 64;
        int wt0 = t0 + w * 16;
        int myq = wt0 + lr;

        bf16x8 qf[16];
        #pragma unroll
        for (int ks = 0; ks < 16; ks++)
            qf[ks] = *(const bf16x8*)&qb[(long)(wt0 + lr) * L_DIM + ks * 32 + lhi * 8];

        f32x4 yacc[8] = {};
        float mrun = -__builtin_inff(), lrun = 0.f;

        int nchunk = (t0 >> 5) + 2;

        if (sel == 0) STAGE_K(0);   // sel=1 prologue staged at end of sel=0 epilogue below

        for (int c = 0; c < nchunk; c++) {
            int s0 = c * 32;
            // B1: this wave's stage loads landed; barrier -> all waves' loads landed
            asm volatile("s_waitcnt vmcnt(0)" ::: "memory");
            __builtin_amdgcn_s_barrier();

            bool active = (s0 < wt0 + 16);   // wave-uniform
            bf16x8 vf[8];
            f32x4 sc[2];
            if (active) {
                // ---- V fragment loads FIRST (oldest in VMEM queue; L2-resident vt) ----
                #pragma unroll
                for (int st = 0; st < 8; st++)
                    vf[st] = *(const bf16x8*)&vtb[(long)(st * 16 + lr) * T_SEQ + s0 + lhi * 8];

                // ---- S^T = K·Q^T: swapped mfma args; lane holds 8 k-values of ONE q-col ----
                __builtin_amdgcn_s_setprio(1);
                #pragma unroll
                for (int ct = 0; ct < 2; ct++) {
                    int swz = lr << 4;                // (row&15)<<4 with row = ct*16+lr
                    const char* kbase = (const char*)Ks + ((ct * 16 + lr) << 10);
                    f32x4 sA = {}, sB = {};
                    #pragma unroll
                    for (int ks = 0; ks < 8; ks++) {
                        bf16x8 kfA = *(const bf16x8*)(kbase + ((ks * 64 + lhi * 16) ^ swz));
                        bf16x8 kfB = *(const bf16x8*)(kbase + (((ks + 8) * 64 + lhi * 16) ^ swz));
                        sA = __builtin_amdgcn_mfma_f32_16x16x32_bf16(kfA, qf[ks], sA, 0, 0, 0);
                        sB = __builtin_amdgcn_mfma_f32_16x16x32_bf16(kfB, qf[ks + 8], sB, 0, 0, 0);
                    }
                    sc[ct] = sA + sB;
                }
                __builtin_amdgcn_s_setprio(0);
            }
            // B2: this wave's K reads retired; barrier -> ALL waves done reading Ks
            asm volatile("s_waitcnt lgkmcnt(0)" ::: "memory");
            __builtin_amdgcn_s_barrier();
            // stage next chunk NOW: latency hides under softmax+PV + other resident block
            if (c + 1 < nchunk) STAGE_K(s0 + 32);

            if (active) {
                // sc[sub][i] = S2[k = s0 + sub*16 + lhi*4 + i][q = wt0 + lr] (base-2 logits)
                float p[2][4];
                #pragma unroll
                for (int sub = 0; sub < 2; sub++)
                    #pragma unroll
                    for (int i = 0; i < 4; i++)
                        p[sub][i] = sc[sub][i];
                // ---- causal mask only in diagonal chunks (wave-uniform branch) ----
                if (s0 + 31 > wt0) {
                    #pragma unroll
                    for (int sub = 0; sub < 2; sub++)
                        #pragma unroll
                        for (int i = 0; i < 4; i++) {
                            int kpos = s0 + sub * 16 + lhi * 4 + i;
                            if (kpos > myq) p[sub][i] = -__builtin_inff();
                        }
                }
                // ---- in-lane row max (8 values) + 2 cross-lane levels ----
                float mx = -__builtin_inff();
                #pragma unroll
                for (int sub = 0; sub < 2; sub++)
                    #pragma unroll
                    for (int i = 0; i < 4; i++)
                        mx = fmaxf(mx, p[sub][i]);
                mx = fmaxf(mx, __shfl_xor(mx, 16));
                mx = fmaxf(mx, __shfl_xor(mx, 32));

                // defer-rescale (exact, THR=0): skip yacc pass when no q-col max grew
                unsigned long long grew = __ballot(mx > mrun);
                if (grew) {
                    float mnew = fmaxf(mrun, mx);
                    float fac = exp2f(mrun - mnew);
                    mrun = mnew;
                    lrun *= fac;
                    float facr[4];
                    #pragma unroll
                    for (int i = 0; i < 4; i++)
                        facr[i] = __shfl(fac, lhi * 4 + i);    // fac of q-row lhi*4+i
                    #pragma unroll
                    for (int st = 0; st < 8; st++)
                        #pragma unroll
                        for (int i = 0; i < 4; i++)
                            yacc[st][i] *= facr[i];
                }
                float ls = 0.f;
                #pragma unroll
                for (int sub = 0; sub < 2; sub++)
                    #pragma unroll
                    for (int i = 0; i < 4; i++) {
                        p[sub][i] = exp2f(p[sub][i] - mrun);
                        ls += p[sub][i];
                    }
                ls += __shfl_xor(ls, 16);
                ls += __shfl_xor(ls, 32);
                lrun += ls;

                // ---- write P^T rows: lane owns row q=lr, cols k=sub*16+lhi*4+{0..3} ----
                int swz = (lr & 3) << 4;
                char* pb = Pwb + lr * 64;
                #pragma unroll
                for (int sub = 0; sub < 2; sub++) {
                    short4v pk;
                    #pragma unroll
                    for (int i = 0; i < 4; i++) pk[i] = f2bf(p[sub][i]);
                    *(short4v*)(pb + ((sub * 32 + lhi * 8) ^ swz)) = pk;
                }
                // in-wave RAW through LDS: drain writes + fence scheduler (rule #18)
                asm volatile("s_waitcnt lgkmcnt(0)" ::: "memory");
                __builtin_amdgcn_sched_barrier(0);
                // ---- PV: P A-frag read (same swizzle), V from regs ----
                bf16x8 pf = *(const bf16x8*)(Pwb + lr * 64 + ((lhi * 16) ^ swz));
                __builtin_amdgcn_s_setprio(1);
                #pragma unroll
                for (int st = 0; st < 8; st++)
                    yacc[st] = __builtin_amdgcn_mfma_f32_16x16x32_bf16(pf, vf[st], yacc[st], 0, 0, 0);
                __builtin_amdgcn_s_setprio(0);
            }
        }

        // stage the next sweep's first chunk (all Ks reads of this sweep retired at last B2)
        if (sel == 0) STAGE_K(0);

        // lrun lives at q=lr lanes; redistribute to yacc's q=lhi*4+i rows
        float lrunr[4];
        #pragma unroll
        for (int i = 0; i < 4; i++)
            lrunr[i] = __shfl(lrun, lhi * 4 + i);
        #pragma unroll
        for (int st = 0; st < 8; st++)
            #pragma unroll
            for (int i = 0; i < 4; i++) {
                int trow = wt0 + lhi * 4 + i;
                float val = yacc[st][i] / lrunr[i];
                y[((long)(b * T_SEQ + trow)) * C_DIM + h * S_DIM + st * 16 + lr] = f2bf(val);
            }
    }
#undef STAGE_K
}

extern "C" void kernel_launch(void* const* d_in, const int* in_sizes, int n_in,
                              void* d_out, int out_size, void* d_ws, size_t ws_size,
                              hipStream_t stream) {
    const float* x    = (const float*)d_in[0];
    const float* wdkv = (const float*)d_in[1];
    const float* wuk  = (const float*)d_in[2];
    const float* wuv  = (const float*)d_in[3];
    const float* wq   = (const float*)d_in[4];
    const float* wo   = (const float*)d_in[5];
    float* out = (float*)d_out;

    short* ws = (short*)d_ws;
    size_t off = 0;
    short* xb    = ws + off; off += (size_t)4096 * 2048;   // x bf16 [B*T][C]   (reused as vt)
    short* wqT   = ws + off; off += (size_t)2048 * 2048;   // [C_out][C_in]
    short* wdkvT = ws + off; off += (size_t)512 * 2048;    // [L][C]
    short* wukT  = ws + off; off += (size_t)512 * 2048;    // [L][C]
    short* wuvT  = ws + off; off += (size_t)2048 * 512;    // [C][L]
    short* woT   = ws + off; off += (size_t)2048 * 2048;   // [C][C]
    short* q     = ws + off; off += (size_t)4096 * 2048;   // [B*T][C]         (reused as y)
    short* kvb   = ws + off; off += (size_t)4096 * 512;    // [B*T][L]
    short* vbuf  = ws + off; off += (size_t)4096 * 2048;   // [B*T][C] (unused now)
    short* qlat  = ws + off; off += (size_t)H_NUM * B_SZ * T_SEQ * L_DIM; // [H][B][T][L]
    short* vtb  = xb;   // vt [B][H][S][T], aliases xb (dead after gemm2a)
    short* ybuf = q;    // y  [B][T][C],   aliases q  (dead by then)
    (void)vbuf;

    const float qscale = 0.022097086912079608f * 1.4426950408889634f;  // 1/sqrt(C) * log2(e)

    // fused prep: x cast + all 5 weight transposes (LDS-tiled)
    prep_kernel<<<11008, 256, 0, stream>>>(x, xb, wq, wqT, wdkv, wdkvT,
                                           wuk, wukT, wuv, wuvT, wo, woT);

    // fused {q, kv}: q = x@wq [4096x2048 k2048] (512 blocks) + kv = x@wdkv [4096x512 k2048] (128)
    gemm2_kernel<<<640, 256, 0, stream>>>(
        xb, wqT, q, 2048, 2048, 2048, 2048, 0, 0, 0, 16, 512, 512, 1.0f, 0,
        xb, wdkvT, kvb, 2048, 2048, 2048, 512, 0, 0, 0, 4, 128, 1.0f, 0);

    // fused {v->vt (transposed store), qlat}: v = kv@wuv [4096x2048 k512] writes vt directly;
    // qlat[h] = q_h@wuk_h [4096x512 k128] x16 heads, pre-scaled by qscale
    gemm2_kernel<<<2560, 256, 0, stream>>>(
        kvb, wuvT, vtb, 512, 512, 512, 2048, 0, 0, 0, 16, 512, 512, 1.0f, 1,
        q, wukT, qlat, 128, 2048, 2048, 512, 128, 128, (long)B_SZ * T_SEQ * L_DIM, 4, 128, qscale, 0);

    // flash attention v18 (paired, XCD-mapped, setprio) -> y [B][T][C]
    flash13_kernel<<<dim3(512, 1, 1), 256, 0, stream>>>(qlat, kvb, vtb, ybuf);
    // out = y @ w_o [4096 x 2048] k=2048, fp32 out
    gemm_bt_kernel<<<dim3(16, 32, 1), 256, 0, stream>>>(ybuf, woT, out, 2048, 2048, 2048, 2048);
}

// Round 20
// 348.268 us; speedup vs baseline: 1.0680x; 1.0680x over previous
//
#include <hip/hip_runtime.h>
#include <hip/hip_bf16.h>

#define T_SEQ 2048
#define C_DIM 2048
#define L_DIM 512
#define H_NUM 16
#define S_DIM 128
#define B_SZ  2

typedef __attribute__((ext_vector_type(8))) short bf16x8;
typedef __attribute__((ext_vector_type(4))) float f32x4;
typedef __attribute__((ext_vector_type(4))) short short4v;

__device__ inline short f2bf(float f) {
    union { float f; unsigned u; } x; x.f = f;
    unsigned r = x.u + 0x7fffu + ((x.u >> 16) & 1u);
    return (short)(r >> 16);
}

// ---------- LDS-tiled weight transpose: in fp32 [R][C] -> out bf16 [C][R], 64x64 tiles ----------
__device__ __forceinline__ void wtile_body(const float* __restrict__ in, short* __restrict__ out,
                                           int R, int C, int r0, int c0, int tid) {
    __shared__ float lds[64][66];
    #pragma unroll
    for (int it = 0; it < 4; it++) {
        int r = (tid >> 4) + it * 16;
        int c4 = (tid & 15) * 4;
        float4 v = *(const float4*)&in[(long)(r0 + r) * C + c0 + c4];
        lds[c4 + 0][r] = v.x; lds[c4 + 1][r] = v.y;
        lds[c4 + 2][r] = v.z; lds[c4 + 3][r] = v.w;
    }
    __syncthreads();
    #pragma unroll
    for (int it = 0; it < 4; it++) {
        int c = tid >> 2;
        int rb = (tid & 3) * 16 + it * 4;
        short4v o;
        #pragma unroll
        for (int j = 0; j < 4; j++) o[j] = f2bf(lds[c][rb + j]);
        *(short4v*)&out[(long)(c0 + c) * R + r0 + rb] = o;
    }
}

// ---------- fused prep: x cast (blocks 0..8191) + 5 tiled weight transposes (8192..11007) ------
__global__ __launch_bounds__(256) void prep_kernel(
    const float* __restrict__ x, short* __restrict__ xb,
    const float* __restrict__ wq, short* __restrict__ wqT,
    const float* __restrict__ wdkv, short* __restrict__ wdkvT,
    const float* __restrict__ wuk, short* __restrict__ wukT,
    const float* __restrict__ wuv, short* __restrict__ wuvT,
    const float* __restrict__ wo, short* __restrict__ woT)
{
    int bid = blockIdx.x, tid = threadIdx.x;
    if (bid < 8192) {
        int i = bid * 256 + tid;                       // 8192*256 == 2097152 exactly
        float4 v = ((const float4*)x)[i];
        short4v o;
        o[0] = f2bf(v.x); o[1] = f2bf(v.y); o[2] = f2bf(v.z); o[3] = f2bf(v.w);
        ((short4v*)xb)[i] = o;
        return;
    }
    int t = bid - 8192;
    if (t < 1024)       wtile_body(wq,   wqT,   2048, 2048, (t >> 5) * 64,            (t & 31) * 64, tid);
    else if (t < 1280)  wtile_body(wdkv, wdkvT, 2048, 512,  ((t - 1024) >> 3) * 64,   ((t - 1024) & 7) * 64, tid);
    else if (t < 1536)  wtile_body(wuk,  wukT,  2048, 512,  ((t - 1280) >> 3) * 64,   ((t - 1280) & 7) * 64, tid);
    else if (t < 1792)  wtile_body(wuv,  wuvT,  512,  2048, ((t - 1536) >> 5) * 64,   ((t - 1536) & 31) * 64, tid);
    else                wtile_body(wo,   woT,   2048, 2048, ((t - 1792) >> 5) * 64,   ((t - 1792) & 31) * 64, tid);
}

// ---------- GEMM body: 128x128 tile, BK=32, dbuf LDS + counted vmcnt(4); cscale on output ------
// transout: epilogue transposes the tile via LDS (As reused as exactly-32KB scratch) and stores
// directly in vt[b][col][t] layout (b = m0>>11), coalesced b128. XOR swizzle row^((col&7)<<3).
__device__ __forceinline__ void gemm_body(
    const short* __restrict__ A, const short* __restrict__ Bt,
    float* __restrict__ Cf, short* __restrict__ Cb,
    int K, int lda, int ldb, int ldc, int m0, int n0, long coff, bool outf32, bool transout,
    float cscale, short (&As)[2][128 * 32], short (&Bs)[2][128 * 32])
{
    int tid = threadIdx.x;
    int wave = tid >> 6, l = tid & 63;
    int wm = (wave >> 1) * 64, wn = (wave & 1) * 64;
    int lr = l & 15, lhi = l >> 4;
    f32x4 acc[4][4] = {};

#define STAGE_AB(KI, BUF) do { \
        _Pragma("unroll") \
        for (int r = 0; r < 2; r++) { \
            int e = (r * 256 + tid) * 8; \
            int row = e >> 5, col = e & 31; \
            __builtin_amdgcn_global_load_lds( \
                (const __attribute__((address_space(1))) unsigned int*)(A + (long)(m0 + row) * lda + (KI) * 32 + col), \
                (__attribute__((address_space(3))) unsigned int*)(&As[BUF][e]), 16, 0, 0); \
            __builtin_amdgcn_global_load_lds( \
                (const __attribute__((address_space(1))) unsigned int*)(Bt + (long)(n0 + row) * ldb + (KI) * 32 + col), \
                (__attribute__((address_space(3))) unsigned int*)(&Bs[BUF][e]), 16, 0, 0); \
        } \
    } while (0)

    int nk = K >> 5;
    STAGE_AB(0, 0);

    for (int i = 0; i < nk; i++) {
        int cur = i & 1;
        asm volatile("s_waitcnt lgkmcnt(0)" ::: "memory");
        __builtin_amdgcn_s_barrier();
        if (i + 1 < nk) {
            STAGE_AB(i + 1, cur ^ 1);
            asm volatile("s_waitcnt vmcnt(4)" ::: "memory");
        } else {
            asm volatile("s_waitcnt vmcnt(0)" ::: "memory");
        }
        __builtin_amdgcn_s_barrier();

        bf16x8 af[4], bfr[4];
        #pragma unroll
        for (int mt = 0; mt < 4; mt++)
            af[mt] = *(const bf16x8*)&As[cur][(wm + mt * 16 + lr) * 32 + lhi * 8];
        #pragma unroll
        for (int nt = 0; nt < 4; nt++)
            bfr[nt] = *(const bf16x8*)&Bs[cur][(wn + nt * 16 + lr) * 32 + lhi * 8];
        #pragma unroll
        for (int mt = 0; mt < 4; mt++)
            #pragma unroll
            for (int nt = 0; nt < 4; nt++)
                acc[mt][nt] = __builtin_amdgcn_mfma_f32_16x16x32_bf16(af[mt], bfr[nt], acc[mt][nt], 0, 0, 0);
    }
#undef STAGE_AB

    if (!transout) {
        #pragma unroll
        for (int mt = 0; mt < 4; mt++) {
            #pragma unroll
            for (int i = 0; i < 4; i++) {
                int row = m0 + wm + mt * 16 + lhi * 4 + i;
                long base = coff + (long)row * ldc + n0 + wn;
                #pragma unroll
                for (int nt = 0; nt < 4; nt++) {
                    float val = acc[mt][nt][i] * cscale;
                    int colo = nt * 16 + lr;
                    if (outf32) Cf[base + colo] = val;
                    else        Cb[base + colo] = f2bf(val);
                }
            }
        }
    } else {
        // transpose tile in LDS, then coalesced store to vt[b][col][t]
        __syncthreads();
        short* sc = &As[0][0];                         // 128*128 shorts = exactly 32KB
        #pragma unroll
        for (int mt = 0; mt < 4; mt++) {
            int rowb = wm + mt * 16 + lhi * 4;
            #pragma unroll
            for (int nt = 0; nt < 4; nt++) {
                int col = wn + nt * 16 + lr;
                short4v pk;
                #pragma unroll
                for (int i = 0; i < 4; i++) pk[i] = f2bf(acc[mt][nt][i] * cscale);
                *(short4v*)&sc[col * 128 + (rowb ^ ((col & 7) << 3))] = pk;
            }
        }
        __syncthreads();
        long base = (long)(m0 >> 11) * T_SEQ * C_DIM + (m0 & 2047);
        #pragma unroll
        for (int it = 0; it < 8; it++) {
            int flat = it * 2048 + tid * 8;
            int col = flat >> 7, rowb = flat & 127;
            bf16x8 o = *(const bf16x8*)&sc[col * 128 + (rowb ^ ((col & 7) << 3))];
            *(bf16x8*)&Cb[base + (long)(n0 + col) * T_SEQ + rowb] = o;
        }
    }
}

// ---------- single-problem GEMM (used for the final out = y @ w_o, fp32 out) ----------
__global__ __launch_bounds__(256) void gemm_bt_kernel(
    const short* __restrict__ A, const short* __restrict__ Bt, float* __restrict__ Cf,
    int K, int lda, int ldb, int ldc)
{
    __shared__ __align__(16) short As[2][128 * 32];
    __shared__ __align__(16) short Bs[2][128 * 32];
    int m0 = blockIdx.y * 128, n0 = blockIdx.x * 128;
    gemm_body(A, Bt, Cf, nullptr, K, lda, ldb, ldc, m0, n0, 0, true, false, 1.0f, As, Bs);
}

// ---------- fused 2-problem GEMM: p0 blocks [0,nblk0), p1 after (1D decoded grid) ----------
__global__ __launch_bounds__(256) void gemm2_kernel(
    const short* A0, const short* Bt0, short* Cb0, int K0, int lda0, int ldb0, int ldc0,
    long sAz0, long sBz0, long sCz0, int nx0, int nxy0, int nblk0, float cscale0, int trans0,
    const short* A1, const short* Bt1, short* Cb1, int K1, int lda1, int ldb1, int ldc1,
    long sAz1, long sBz1, long sCz1, int nx1, int nxy1, float cscale1, int trans1)
{
    __shared__ __align__(16) short As[2][128 * 32];
    __shared__ __align__(16) short Bs[2][128 * 32];
    int id = blockIdx.x;
    const short *A, *Bt; short* Cb; int K, lda, ldb, ldc, nx, nxy, local, trans;
    long sAz, sBz, sCz; float cs;
    if (id < nblk0) {
        A = A0; Bt = Bt0; Cb = Cb0; K = K0; lda = lda0; ldb = ldb0; ldc = ldc0;
        sAz = sAz0; sBz = sBz0; sCz = sCz0; nx = nx0; nxy = nxy0; local = id; cs = cscale0;
        trans = trans0;
    } else {
        A = A1; Bt = Bt1; Cb = Cb1; K = K1; lda = lda1; ldb = ldb1; ldc = ldc1;
        sAz = sAz1; sBz = sBz1; sCz = sCz1; nx = nx1; nxy = nxy1; local = id - nblk0; cs = cscale1;
        trans = trans1;
    }
    int z = local / nxy, rem = local % nxy;
    int n0 = (rem % nx) * 128, m0 = (rem / nx) * 128;
    A += (long)z * sAz; Bt += (long)z * sBz;
    gemm_body(A, Bt, nullptr, Cb, K, lda, ldb, ldc, m0, n0, (long)z * sCz, false, trans != 0,
              cs, As, Bs);
}

// ------------- flash attention v17 (restored): XCD map + paired tiles + exp2 softmax diet -----
__global__ __launch_bounds__(256) void flash13_kernel(
    const short* __restrict__ qlat,  // [H][B][T][L]  (pre-scaled by 1/sqrt(C)*log2(e))
    const short* __restrict__ kv,    // [B][T][L]
    const short* __restrict__ vt,    // [B][H][S][T]
    short* __restrict__ y)           // [B][T][C]
{
    __shared__ __align__(16) short Ks[32 * 512];      // 32 KB, single buffer
    __shared__ __align__(16) short Ps[4 * 16 * 32];   // 4 KB (1 KB per wave, wave-private)

    int f = blockIdx.x;                               // 0..511
    int xcd = f & 7, slot = f >> 3;
    int b = xcd >> 2;
    int h = (xcd & 3) | ((slot >> 4) << 2);
    int pr = slot & 15;
    int tid = threadIdx.x;
    int w = tid >> 6, l = tid & 63, lr = l & 15, lhi = l >> 4;
    const short* qb  = qlat + ((long)(h * B_SZ + b)) * T_SEQ * L_DIM;
    const short* kvb = kv + (long)b * T_SEQ * L_DIM;
    const short* vtb = vt + ((long)(b * H_NUM + h)) * S_DIM * T_SEQ;
    char* Pwb = (char*)(Ps + w * 512);

    // stage chunk [32 rows] at kv row S0ROW into Ks (src pre-swizzled, dest linear; rule #21)
#define STAGE_K(S0ROW) do { \
        _Pragma("unroll") \
        for (int r = 0; r < 8; r++) { \
            int flat = r * 4096 + tid * 16; \
            int row = flat >> 10, colb = flat & 1023; \
            int src = (((S0ROW) + row) << 10) + (colb ^ ((row & 15) << 4)); \
            __builtin_amdgcn_global_load_lds( \
                (const __attribute__((address_space(1))) unsigned int*)((const char*)kvb + src), \
                (__attribute__((address_space(3))) unsigned int*)((char*)Ks + flat), 16, 0, 0); \
        } \
    } while (0)

    #pragma unroll 1
    for (int sel = 0; sel < 2; sel++) {
        int qt = sel ? pr : (31 - pr);                // heavy tile first
        int t0 = qt * 64;
        int wt0 = t0 + w * 16;
        int myq = wt0 + lr;

        bf16x8 qf[16];
        #pragma unroll
        for (int ks = 0; ks < 16; ks++)
            qf[ks] = *(const bf16x8*)&qb[(long)(wt0 + lr) * L_DIM + ks * 32 + lhi * 8];

        f32x4 yacc[8] = {};
        float mrun = -__builtin_inff(), lrun = 0.f;

        int nchunk = (t0 >> 5) + 2;

        if (sel == 0) STAGE_K(0);   // sel=1 prologue staged at end of sel=0 epilogue below

        for (int c = 0; c < nchunk; c++) {
            int s0 = c * 32;
            // B1: this wave's stage loads landed; barrier -> all waves' loads landed
            asm volatile("s_waitcnt vmcnt(0)" ::: "memory");
            __builtin_amdgcn_s_barrier();

            bool active = (s0 < wt0 + 16);   // wave-uniform
            bf16x8 vf[8];
            f32x4 sc[2];
            if (active) {
                // ---- V fragment loads FIRST (oldest in VMEM queue; L2-resident vt) ----
                #pragma unroll
                for (int st = 0; st < 8; st++)
                    vf[st] = *(const bf16x8*)&vtb[(long)(st * 16 + lr) * T_SEQ + s0 + lhi * 8];

                // ---- S^T = K·Q^T: swapped mfma args; lane holds 8 k-values of ONE q-col ----
                #pragma unroll
                for (int ct = 0; ct < 2; ct++) {
                    int swz = lr << 4;                // (row&15)<<4 with row = ct*16+lr
                    const char* kbase = (const char*)Ks + ((ct * 16 + lr) << 10);
                    f32x4 sA = {}, sB = {};
                    #pragma unroll
                    for (int ks = 0; ks < 8; ks++) {
                        bf16x8 kfA = *(const bf16x8*)(kbase + ((ks * 64 + lhi * 16) ^ swz));
                        bf16x8 kfB = *(const bf16x8*)(kbase + (((ks + 8) * 64 + lhi * 16) ^ swz));
                        sA = __builtin_amdgcn_mfma_f32_16x16x32_bf16(kfA, qf[ks], sA, 0, 0, 0);
                        sB = __builtin_amdgcn_mfma_f32_16x16x32_bf16(kfB, qf[ks + 8], sB, 0, 0, 0);
                    }
                    sc[ct] = sA + sB;
                }
            }
            // B2: this wave's K reads retired; barrier -> ALL waves done reading Ks
            asm volatile("s_waitcnt lgkmcnt(0)" ::: "memory");
            __builtin_amdgcn_s_barrier();
            // stage next chunk NOW: latency hides under softmax+PV + other resident block
            if (c + 1 < nchunk) STAGE_K(s0 + 32);

            if (active) {
                // sc[sub][i] = S2[k = s0 + sub*16 + lhi*4 + i][q = wt0 + lr] (base-2 logits)
                float p[2][4];
                #pragma unroll
                for (int sub = 0; sub < 2; sub++)
                    #pragma unroll
                    for (int i = 0; i < 4; i++)
                        p[sub][i] = sc[sub][i];
                // ---- causal mask only in diagonal chunks (wave-uniform branch) ----
                if (s0 + 31 > wt0) {
                    #pragma unroll
                    for (int sub = 0; sub < 2; sub++)
                        #pragma unroll
                        for (int i = 0; i < 4; i++) {
                            int kpos = s0 + sub * 16 + lhi * 4 + i;
                            if (kpos > myq) p[sub][i] = -__builtin_inff();
                        }
                }
                // ---- in-lane row max (8 values) + 2 cross-lane levels ----
                float mx = -__builtin_inff();
                #pragma unroll
                for (int sub = 0; sub < 2; sub++)
                    #pragma unroll
                    for (int i = 0; i < 4; i++)
                        mx = fmaxf(mx, p[sub][i]);
                mx = fmaxf(mx, __shfl_xor(mx, 16));
                mx = fmaxf(mx, __shfl_xor(mx, 32));

                // defer-rescale (exact, THR=0): skip yacc pass when no q-col max grew
                unsigned long long grew = __ballot(mx > mrun);
                if (grew) {
                    float mnew = fmaxf(mrun, mx);
                    float fac = exp2f(mrun - mnew);
                    mrun = mnew;
                    lrun *= fac;
                    float facr[4];
                    #pragma unroll
                    for (int i = 0; i < 4; i++)
                        facr[i] = __shfl(fac, lhi * 4 + i);    // fac of q-row lhi*4+i
                    #pragma unroll
                    for (int st = 0; st < 8; st++)
                        #pragma unroll
                        for (int i = 0; i < 4; i++)
                            yacc[st][i] *= facr[i];
                }
                float ls = 0.f;
                #pragma unroll
                for (int sub = 0; sub < 2; sub++)
                    #pragma unroll
                    for (int i = 0; i < 4; i++) {
                        p[sub][i] = exp2f(p[sub][i] - mrun);
                        ls += p[sub][i];
                    }
                ls += __shfl_xor(ls, 16);
                ls += __shfl_xor(ls, 32);
                lrun += ls;

                // ---- write P^T rows: lane owns row q=lr, cols k=sub*16+lhi*4+{0..3} ----
                int swz = (lr & 3) << 4;
                char* pb = Pwb + lr * 64;
                #pragma unroll
                for (int sub = 0; sub < 2; sub++) {
                    short4v pk;
                    #pragma unroll
                    for (int i = 0; i < 4; i++) pk[i] = f2bf(p[sub][i]);
                    *(short4v*)(pb + ((sub * 32 + lhi * 8) ^ swz)) = pk;
                }
                // in-wave RAW through LDS: drain writes + fence scheduler (rule #18)
                asm volatile("s_waitcnt lgkmcnt(0)" ::: "memory");
                __builtin_amdgcn_sched_barrier(0);
                // ---- PV: P A-frag read (same swizzle), V from regs ----
                bf16x8 pf = *(const bf16x8*)(Pwb + lr * 64 + ((lhi * 16) ^ swz));
                #pragma unroll
                for (int st = 0; st < 8; st++)
                    yacc[st] = __builtin_amdgcn_mfma_f32_16x16x32_bf16(pf, vf[st], yacc[st], 0, 0, 0);
            }
        }

        // stage the next sweep's first chunk (all Ks reads of this sweep retired at last B2)
        if (sel == 0) STAGE_K(0);

        // lrun lives at q=lr lanes; redistribute to yacc's q=lhi*4+i rows
        float lrunr[4];
        #pragma unroll
        for (int i = 0; i < 4; i++)
            lrunr[i] = __shfl(lrun, lhi * 4 + i);
        #pragma unroll
        for (int st = 0; st < 8; st++)
            #pragma unroll
            for (int i = 0; i < 4; i++) {
                int trow = wt0 + lhi * 4 + i;
                float val = yacc[st][i] / lrunr[i];
                y[((long)(b * T_SEQ + trow)) * C_DIM + h * S_DIM + st * 16 + lr] = f2bf(val);
            }
    }
#undef STAGE_K
}

extern "C" void kernel_launch(void* const* d_in, const int* in_sizes, int n_in,
                              void* d_out, int out_size, void* d_ws, size_t ws_size,
                              hipStream_t stream) {
    const float* x    = (const float*)d_in[0];
    const float* wdkv = (const float*)d_in[1];
    const float* wuk  = (const float*)d_in[2];
    const float* wuv  = (const float*)d_in[3];
    const float* wq   = (const float*)d_in[4];
    const float* wo   = (const float*)d_in[5];
    float* out = (float*)d_out;

    short* ws = (short*)d_ws;
    size_t off = 0;
    short* xb    = ws + off; off += (size_t)4096 * 2048;   // x bf16 [B*T][C]   (reused as vt)
    short* wqT   = ws + off; off += (size_t)2048 * 2048;   // [C_out][C_in]
    short* wdkvT = ws + off; off += (size_t)512 * 2048;    // [L][C]
    short* wukT  = ws + off; off += (size_t)512 * 2048;    // [L][C]
    short* wuvT  = ws + off; off += (size_t)2048 * 512;    // [C][L]
    short* woT   = ws + off; off += (size_t)2048 * 2048;   // [C][C]
    short* q     = ws + off; off += (size_t)4096 * 2048;   // [B*T][C]         (reused as y)
    short* kvb   = ws + off; off += (size_t)4096 * 512;    // [B*T][L]
    short* vbuf  = ws + off; off += (size_t)4096 * 2048;   // [B*T][C] (unused now)
    short* qlat  = ws + off; off += (size_t)H_NUM * B_SZ * T_SEQ * L_DIM; // [H][B][T][L]
    short* vtb  = xb;   // vt [B][H][S][T], aliases xb (dead after gemm2a)
    short* ybuf = q;    // y  [B][T][C],   aliases q  (dead by then)
    (void)vbuf;

    const float qscale = 0.022097086912079608f * 1.4426950408889634f;  // 1/sqrt(C) * log2(e)

    // fused prep: x cast + all 5 weight transposes (LDS-tiled)
    prep_kernel<<<11008, 256, 0, stream>>>(x, xb, wq, wqT, wdkv, wdkvT,
                                           wuk, wukT, wuv, wuvT, wo, woT);

    // fused {q, kv}: q = x@wq [4096x2048 k2048] (512 blocks) + kv = x@wdkv [4096x512 k2048] (128)
    gemm2_kernel<<<640, 256, 0, stream>>>(
        xb, wqT, q, 2048, 2048, 2048, 2048, 0, 0, 0, 16, 512, 512, 1.0f, 0,
        xb, wdkvT, kvb, 2048, 2048, 2048, 512, 0, 0, 0, 4, 128, 1.0f, 0);

    // fused {v->vt (transposed store), qlat}: v = kv@wuv [4096x2048 k512] writes vt directly;
    // qlat[h] = q_h@wuk_h [4096x512 k128] x16 heads, pre-scaled by qscale
    gemm2_kernel<<<2560, 256, 0, stream>>>(
        kvb, wuvT, vtb, 512, 512, 512, 2048, 0, 0, 0, 16, 512, 512, 1.0f, 1,
        q, wukT, qlat, 128, 2048, 2048, 512, 128, 128, (long)B_SZ * T_SEQ * L_DIM, 4, 128, qscale, 0);

    // flash attention v17 (paired, XCD-mapped, exp2 diet, NO setprio) -> y [B][T][C]
    flash13_kernel<<<dim3(512, 1, 1), 256, 0, stream>>>(qlat, kvb, vtb, ybuf);
    // out = y @ w_o [4096 x 2048] k=2048, fp32 out
    gemm_bt_kernel<<<dim3(16, 32, 1), 256, 0, stream>>>(ybuf, woT, out, 2048, 2048, 2048, 2048);
}